// Round 19
// baseline (801.249 us; speedup 1.0000x reference)
//
#include <hip/hip_runtime.h>
#include <hip/hip_bf16.h>

#define NPTS 600000
#define NKEYS (1 << 22)          // 2 * 128^3 compact key space
#define CHUNK 4096
#define NPART (NKEYS / CHUNK)    // 1024

typedef unsigned int u32;
typedef unsigned short u16;
typedef __attribute__((ext_vector_type(8))) short short8;   // 8 bf16 = 4 VGPRs
typedef __attribute__((ext_vector_type(4))) int i32x4;      // 16B asm load dst
typedef __attribute__((ext_vector_type(4))) float f32x4;

__device__ __forceinline__ u16 f2bf(float x) {
  union { float f; u32 u; } c; c.f = x;
  u32 r = c.u + 0x7fffu + ((c.u >> 16) & 1u);   // RNE, inputs finite
  return (u16)(r >> 16);
}

// ---- K0a: fold BN into alpha/beta -------------------------------------------
__global__ void k0a_bn(const float* __restrict__ s, const float* __restrict__ b,
                       const float* __restrict__ m, const float* __restrict__ v,
                       float* __restrict__ ab) {
  int c = threadIdx.x;   // 64 threads
  float a = s[c] * rsqrtf(v[c] + 1e-5f);
  ab[c] = a;
  ab[64 + c] = b[c] - m[c] * a;
}

// ---- K0b: W[27][cin][cout] f32 -> Wt[27][cout][cin] bf16 --------------------
__global__ void k0b_wt(const float* __restrict__ W, u16* __restrict__ Wt) {
  int e = blockIdx.x * 256 + threadIdx.x;
  if (e >= 27 * 4096) return;
  int k = e >> 12, rem = e & 4095, cin = rem >> 6, cout = rem & 63;
  Wt[(k << 12) + (cout << 6) + cin] = f2bf(W[e]);
}

// ---- K1: compact keys + per-voxel counts + per-chunk unique counts ----------
__global__ void k1_keys(const int* __restrict__ coords, int* __restrict__ keys,
                        u32* __restrict__ lut, u32* __restrict__ partials) {
  int i = blockIdx.x * 256 + threadIdx.x;
  if (i >= NPTS) return;
  int4 c4 = *(const int4*)(coords + i * 4);
  int k = (c4.w << 21) | ((c4.x >> 1) << 14) | ((c4.y >> 1) << 7) | (c4.z >> 1);
  keys[i] = k;
  u32 old = atomicAdd(&lut[k], 1u);          // count points per voxel
  if (old == 0u) atomicAdd(&partials[k >> 12], 1u);   // first toucher counts
}

// ---- K2b: scan the 1024 partials (exclusive) + total U ----------------------
__global__ void k2b_top(u32* __restrict__ partials) {
  __shared__ u32 sh[NPART];
  int t = threadIdx.x;   // 1024 threads
  u32 x = partials[t];
  sh[t] = x; __syncthreads();
  for (int off = 1; off < NPART; off <<= 1) {
    u32 add = (t >= off) ? sh[t - off] : 0u;
    __syncthreads();
    sh[t] += add;
    __syncthreads();
  }
  partials[t] = sh[t] - x;                       // exclusive
  if (t == NPART - 1) partials[NPART] = sh[t];   // total unique count U
}

// ---- K2c: fill lut ((rank+1)|multi<<31 or 0), r2k, zero multi f32 rows ------
__global__ void k2c_fill(u32* __restrict__ lut, const u32* __restrict__ partials,
                         int* __restrict__ r2k, float* __restrict__ fds32) {
  __shared__ u32 tsum[256];
  int blk = blockIdx.x, t = threadIdx.x;
  int base = blk * CHUNK + t * 16;
  u32 loc[16]; u32 s = 0;
#pragma unroll
  for (int j = 0; j < 16; j++) { loc[j] = lut[base + j]; s += (loc[j] != 0u); }
  tsum[t] = s; __syncthreads();
  for (int off = 1; off < 256; off <<= 1) {
    u32 add = (t >= off) ? tsum[t - off] : 0u;
    __syncthreads();
    tsum[t] += add;
    __syncthreads();
  }
  u32 rank = partials[blk] + tsum[t] - s;   // exclusive rank for first elem
#pragma unroll
  for (int j = 0; j < 16; j++) {
    if (loc[j]) {
      u32 flag = (loc[j] > 1u) ? 0x80000000u : 0u;
      lut[base + j] = (rank + 1u) | flag;
      r2k[rank] = base + j;
      if (flag) {   // zero the f32 accumulation row for multi-point voxels
        float4 z = {0.f, 0.f, 0.f, 0.f};
        float* d = fds32 + ((size_t)rank << 6);
#pragma unroll
        for (int c = 0; c < 16; c++) *(float4*)(d + c * 4) = z;
      }
      rank++;
    } else lut[base + j] = 0u;
  }
}

// ---- K3: fused segment-sum: singles -> bf16 direct, multis -> f32 atomics ---
__global__ void k3_seg(const float* __restrict__ feats, const int* __restrict__ keys,
                       const u32* __restrict__ lut, float* __restrict__ fds32,
                       u16* __restrict__ fdsb) {
  int idx = blockIdx.x * 256 + threadIdx.x;   // NPTS*16 threads, 4 ch each
  if (idx >= NPTS * 16) return;
  int i = idx >> 4, q = (idx & 15) << 2;
  u32 lv = lut[keys[i]];
  u32 r = (lv & 0x7fffffffu) - 1u;
  float4 v = *(const float4*)(feats + (size_t)i * 64 + q);
  if (lv >> 31) {               // ~13% of points: shared voxel, accumulate f32
    float* dst = fds32 + ((size_t)r << 6) + q;
    atomicAdd(dst + 0, v.x); atomicAdd(dst + 1, v.y);
    atomicAdd(dst + 2, v.z); atomicAdd(dst + 3, v.w);
  } else {                      // ~87%: sole occupant, convert + plain store
    ushort4 o;
    o.x = f2bf(v.x); o.y = f2bf(v.y); o.z = f2bf(v.z); o.w = f2bf(v.w);
    *(ushort4*)(fdsb + ((size_t)r << 6) + q) = o;
  }
}

// ---- K3b: convert only multi-voxel rows f32 -> bf16 -------------------------
__global__ void k3b_fix(const int* __restrict__ r2k, const u32* __restrict__ lut,
                        const u32* __restrict__ pU,
                        const float* __restrict__ fds32, u16* __restrict__ fdsb) {
  int idx = blockIdx.x * 256 + threadIdx.x;   // NPTS*4 threads, 16 ch each
  int r = idx >> 2;
  if (r >= (int)(*pU)) return;
  u32 lv = lut[r2k[r]];
  if (!(lv >> 31)) return;
  int q = (idx & 3) << 4;
  const float* src = fds32 + ((size_t)r << 6) + q;
  u16* dst = fdsb + ((size_t)r << 6) + q;
#pragma unroll
  for (int j = 0; j < 4; j++) {
    float4 v = *(const float4*)(src + j * 4);
    ushort4 o;
    o.x = f2bf(v.x); o.y = f2bf(v.y); o.z = f2bf(v.z); o.w = f2bf(v.w);
    *(ushort4*)(dst + j * 4) = o;
  }
}

// ---- K4: symmetric-wave gather-GEMM, 2x2 consumer split ---------------------
// Block = 256 thr (4 symmetric waves), 64 output rows. R15 producer (wave
// gathers its 16 rows, 4 lanes/row, branchless zero-row sentinel, volatile
// asm + counted vmcnt). Consumer change vs R15: wave w = quadrant
// (wi=w>>1 rows, wj=w&1 couts) -> 32 rows x 32 couts. A-LDS-reads HALVE
// (4/wave vs 8): LDS pipe was ~64% of the per-interval CU budget (40 wave
// ops x ~12cyc vs 745cyc/interval); now 24 ops (~39%). B doubles to 4
// loads/wave (L1-hot, cheap). Schedule: P(T)@T-5, L(T)@T-3, B(T)@T-2,
// DSW(T)@T-1, consume@T. batch(J)={L(J+3):2,P(J+5):1,B(J+2):4}=7;
// NW(K)=|batch(K-1)|=2[K+2<27]+1[K+4<27]+4[K+1<27]. LDS ring-2, verified
// bank rotation. m204 bijective XCD swizzle.
__global__ __launch_bounds__(256) void k4_conv(
    const u32* __restrict__ lut, const int* __restrict__ r2k,
    const u16* __restrict__ fdsb, const u16* __restrict__ Wt,
    const u32* __restrict__ pU, const float* __restrict__ ab,
    float* __restrict__ out) {
  __shared__ __align__(16) char ldsA[2][8192];   // ring-2: 64 rows x 128B
  const u32 U = *pU;
  int tid = threadIdx.x;
  int w = tid >> 6, l = tid & 63;
  // m204 bijective XCD swizzle (grid 9375 not divisible by 8)
  int bid = blockIdx.x;
  int nwg = (int)gridDim.x, q = nwg >> 3, rr = nwg & 7;
  int xcd = bid & 7, t8 = bid >> 3;
  int swz = (xcd < rr ? xcd * (q + 1) : rr * (q + 1) + (xcd - rr) * q) + t8;
  int rbase = swz * 64;

  int lr = (w << 4) + (l >> 2);        // this lane's produced row (0..63)
  int bo = (l & 3) << 5;               // byte offset within the 128B row
  int col = l & 15, kg = l >> 4;
  int wi = w >> 1, wj = w & 1;         // consumer quadrant: rows / couts

  // key decode for produced row (4 lanes/row)
  int key = -1, x = 0, y = 0, z = 0;
  {
    int r = rbase + lr;
    key = ((u32)r < U) ? r2k[r] : -1;
    z = key & 127; y = (key >> 7) & 127; x = (key >> 14) & 127;
  }

  u32 lvr[4];        // probe ring: P(T)@T-5 -> L(T)@T-3
  i32x4 rgA[3][2];   // gather ring: L(T)@T-3 -> DSW(T)@T-1
  i32x4 bB[3][4];    // B ring: B(T)@T-2 -> MFMA@T  [ct*2+h]
  f32x4 acc[2][2] = {};   // [rt][ct]

#define P_(T) { \
    const int dx_ = (T) / 9 - 1, dy_ = ((T) / 3) % 3 - 1, dz_ = (T) % 3 - 1; \
    int nx_ = x + dx_, ny_ = y + dy_, nz_ = z + dz_; \
    bool ok_ = (key >= 0) & ((u32)nx_ < 128u) & ((u32)ny_ < 128u) & ((u32)nz_ < 128u); \
    const u32* pp_ = lut + (ok_ ? (key + dx_ * 16384 + dy_ * 128 + dz_) : NKEYS); \
    asm volatile("global_load_dword %0, %1, off" \
                 : "=&v"(lvr[(T) & 3]) : "v"(pp_) : "memory"); }

  // 2x16B gather of this lane's quarter-row; miss -> zero row NPTS
#define L_(T) { \
    u32 lv_ = lvr[(T) & 3]; \
    u32 row_ = lv_ ? ((lv_ & 0x7fffffffu) - 1u) : (u32)NPTS; \
    const char* fr_ = (const char*)(fdsb + ((size_t)row_ << 6)) + bo; \
    asm volatile("global_load_dwordx4 %0, %1, off" \
                 : "=&v"(rgA[(T) % 3][0]) : "v"(fr_) : "memory"); \
    asm volatile("global_load_dwordx4 %0, %1, off offset:16" \
                 : "=&v"(rgA[(T) % 3][1]) : "v"(fr_) : "memory"); }

  // wave's 32-cout B panel: (wj*32 + ct*16 + col) rows of Wt[k], both halves
#define B_(T) { \
    const u16* wb_ = Wt + ((T) << 12) + (((wj << 5) + col) << 6) + (kg << 3); \
    asm volatile("global_load_dwordx4 %0, %1, off" \
                 : "=&v"(bB[(T) % 3][0]) : "v"(wb_) : "memory"); \
    asm volatile("global_load_dwordx4 %0, %1, off offset:64" \
                 : "=&v"(bB[(T) % 3][1]) : "v"(wb_) : "memory"); \
    asm volatile("global_load_dwordx4 %0, %1, off offset:2048" \
                 : "=&v"(bB[(T) % 3][2]) : "v"(wb_) : "memory"); \
    asm volatile("global_load_dwordx4 %0, %1, off offset:2112" \
                 : "=&v"(bB[(T) % 3][3]) : "v"(wb_) : "memory"); }

  // LDS write, R9/R15 bank rotation (rot by row&7)
#define DSW_(T) { \
    char* dst_ = &ldsA[(T) & 1][lr * 128]; \
    int r7_ = lr & 7, c0_ = (l & 3) << 1; \
    *(i32x4*)(dst_ + (((c0_ + r7_) & 7) << 4))     = rgA[(T) % 3][0]; \
    *(i32x4*)(dst_ + (((c0_ + 1 + r7_) & 7) << 4)) = rgA[(T) % 3][1]; }

  // 2x2 quadrant consume: 4 LDS reads, 8 MFMA
#define CONSUME(K) { \
    short8 b00_ = *(short8*)&bB[(K) % 3][0]; \
    short8 b01_ = *(short8*)&bB[(K) % 3][1]; \
    short8 b10_ = *(short8*)&bB[(K) % 3][2]; \
    short8 b11_ = *(short8*)&bB[(K) % 3][3]; \
    const char* slab_ = &ldsA[(K) & 1][0]; \
    _Pragma("unroll") for (int rt = 0; rt < 2; rt++) { \
      int row_ = (wi << 5) + (rt << 4) + col; \
      const char* rp_ = slab_ + row_ * 128; \
      int r7_ = row_ & 7; \
      short8 a0_ = *(const short8*)(rp_ + (((kg + r7_) & 7) << 4)); \
      short8 a1_ = *(const short8*)(rp_ + (((kg + 4 + r7_) & 7) << 4)); \
      acc[rt][0] = __builtin_amdgcn_mfma_f32_16x16x32_bf16(a0_, b00_, acc[rt][0], 0, 0, 0); \
      acc[rt][0] = __builtin_amdgcn_mfma_f32_16x16x32_bf16(a1_, b01_, acc[rt][0], 0, 0, 0); \
      acc[rt][1] = __builtin_amdgcn_mfma_f32_16x16x32_bf16(a0_, b10_, acc[rt][1], 0, 0, 0); \
      acc[rt][1] = __builtin_amdgcn_mfma_f32_16x16x32_bf16(a1_, b11_, acc[rt][1], 0, 0, 0); } }

#define WAITC(N) { asm volatile("s_waitcnt vmcnt(%0)" :: "n"(N) : "memory"); \
                   __builtin_amdgcn_sched_barrier(0); }
#define BAR() { \
    asm volatile("" ::: "memory"); \
    asm volatile("s_waitcnt lgkmcnt(0)" ::: "memory"); \
    __builtin_amdgcn_s_barrier(); \
    asm volatile("" ::: "memory"); }

  // prologue: tile0 -> LDS; batch(-2)={L1,P3,B0}=7, batch(-1)={L2,P4,B1}=7
  P_(0) P_(1) P_(2)
  WAITC(0)
  L_(0)
  WAITC(0)
  DSW_(0)
  L_(1) P_(3) B_(0)
  L_(2) P_(4) B_(1)
  BAR()

  // NW(K) = |batch(K-1)| = 2[K+2<27] + 1[K+4<27] + 4[K+1<27]
#define NW(K) (2 * ((K) + 2 < 27) + 1 * ((K) + 4 < 27) + 4 * ((K) + 1 < 27))
#define BODY(K) { \
    WAITC(NW(K)) \
    if ((K) + 1 < 27) DSW_((K) + 1) \
    if ((K) + 3 < 27) L_((K) + 3) \
    if ((K) + 5 < 27) P_((K) + 5) \
    if ((K) + 2 < 27) B_((K) + 2) \
    CONSUME(K) \
    BAR() }

  BODY(0)  BODY(1)  BODY(2)  BODY(3)  BODY(4)  BODY(5)  BODY(6)
  BODY(7)  BODY(8)  BODY(9)  BODY(10) BODY(11) BODY(12) BODY(13)
  BODY(14) BODY(15) BODY(16) BODY(17) BODY(18) BODY(19) BODY(20)
  BODY(21) BODY(22) BODY(23) BODY(24) BODY(25) BODY(26)

#undef P_
#undef L_
#undef B_
#undef DSW_
#undef CONSUME
#undef WAITC
#undef BAR
#undef NW
#undef BODY

  // epilogue: BN + ReLU for this wave's quadrant, zeros for invalid rows
  {
#pragma unroll
    for (int ct = 0; ct < 2; ct++) {
      int c = (wj << 5) + (ct << 4) + col;
      float al = ab[c], be = ab[64 + c];
#pragma unroll
      for (int rt = 0; rt < 2; rt++) {
#pragma unroll
        for (int i = 0; i < 4; i++) {
          int r = rbase + (wi << 5) + (rt << 4) + (kg << 2) + i;
          if (r >= NPTS) continue;
          bool valid = ((u32)r < U);
          float vv = 0.f;
          if (valid) {
            vv = fmaf(acc[rt][ct][i], al, be);
            vv = vv > 0.f ? vv : 0.f;
          }
          out[((size_t)r << 6) + c] = vv;
        }
      }
    }
  }
}

extern "C" void kernel_launch(void* const* d_in, const int* in_sizes, int n_in,
                              void* d_out, int out_size, void* d_ws, size_t ws_size,
                              hipStream_t stream) {
  const int*   coords = (const int*)d_in[0];
  const float* feats  = (const float*)d_in[1];
  const float* W      = (const float*)d_in[2];
  const float* bns    = (const float*)d_in[3];
  const float* bnb    = (const float*)d_in[4];
  const float* bnm    = (const float*)d_in[5];
  const float* bnv    = (const float*)d_in[6];
  float* out = (float*)d_out;

  char* ws = (char*)d_ws;
  size_t off = 0;
  auto alloc = [&](size_t bytes) -> void* {
    void* p = ws + off;
    off += (bytes + 255) & ~(size_t)255;
    return p;
  };
  u32* lut      = (u32*)alloc((size_t)(NKEYS + 1) * 4);  // +1 zero sentinel
  u32* partials = (u32*)alloc((NPART + 8) * 4);
  int* keys     = (int*)alloc((size_t)NPTS * 4);
  int* r2k      = (int*)alloc((size_t)NPTS * 4);
  u16* fdsb     = (u16*)alloc((size_t)(NPTS + 1) * 64 * 2);  // +1 zero row
  u16* Wt       = (u16*)alloc((size_t)27 * 4096 * 2);
  float* ab     = (float*)alloc(128 * 4);
  (void)ws_size; (void)out_size; (void)n_in; (void)in_sizes;

  float* fds32 = out;   // d_out doubles as f32 staging for multi-point voxels

  hipMemsetAsync(lut, 0, (size_t)(NKEYS + 1) * 4, stream);
  hipMemsetAsync(partials, 0, (NPART + 8) * 4, stream);
  hipMemsetAsync(fdsb + (size_t)NPTS * 64, 0, 128, stream);   // zero row

  k0a_bn<<<1, 64, 0, stream>>>(bns, bnb, bnm, bnv, ab);
  k0b_wt<<<(27 * 4096 + 255) / 256, 256, 0, stream>>>(W, Wt);
  k1_keys<<<(NPTS + 255) / 256, 256, 0, stream>>>(coords, keys, lut, partials);
  k2b_top<<<1, NPART, 0, stream>>>(partials);
  k2c_fill<<<NPART, 256, 0, stream>>>(lut, partials, r2k, fds32);
  k3_seg<<<(NPTS * 16 + 255) / 256, 256, 0, stream>>>(feats, keys, lut, fds32, fdsb);
  k3b_fix<<<(NPTS * 4 + 255) / 256, 256, 0, stream>>>(r2k, lut, partials + NPART, fds32, fdsb);
  // 64 rows per block; 9375 blocks, bijective XCD swizzle in-kernel
  k4_conv<<<(NPTS + 63) / 64, 256, 0, stream>>>(lut, r2k, fdsb, Wt,
                                                partials + NPART, ab, out);
}

// Round 20
// 476.552 us; speedup vs baseline: 1.6813x; 1.6813x over previous
//
#include <hip/hip_runtime.h>
#include <hip/hip_bf16.h>

#define NPTS 600000
#define NKEYS (1 << 22)          // 2 * 128^3 compact key space
#define CHUNK 4096
#define NPART (NKEYS / CHUNK)    // 1024

typedef unsigned int u32;
typedef unsigned short u16;
typedef __attribute__((ext_vector_type(8))) short short8;   // 8 bf16 = 4 VGPRs
typedef __attribute__((ext_vector_type(4))) int i32x4;      // 16B asm load dst
typedef __attribute__((ext_vector_type(4))) float f32x4;

__device__ __forceinline__ u16 f2bf(float x) {
  union { float f; u32 u; } c; c.f = x;
  u32 r = c.u + 0x7fffu + ((c.u >> 16) & 1u);   // RNE, inputs finite
  return (u16)(r >> 16);
}

// ---- K0a: fold BN into alpha/beta -------------------------------------------
__global__ void k0a_bn(const float* __restrict__ s, const float* __restrict__ b,
                       const float* __restrict__ m, const float* __restrict__ v,
                       float* __restrict__ ab) {
  int c = threadIdx.x;   // 64 threads
  float a = s[c] * rsqrtf(v[c] + 1e-5f);
  ab[c] = a;
  ab[64 + c] = b[c] - m[c] * a;
}

// ---- K0b: W[27][cin][cout] f32 -> Wt[27][cout][cin] bf16 --------------------
__global__ void k0b_wt(const float* __restrict__ W, u16* __restrict__ Wt) {
  int e = blockIdx.x * 256 + threadIdx.x;
  if (e >= 27 * 4096) return;
  int k = e >> 12, rem = e & 4095, cin = rem >> 6, cout = rem & 63;
  Wt[(k << 12) + (cout << 6) + cin] = f2bf(W[e]);
}

// ---- K1: compact keys + per-voxel point counts ------------------------------
__global__ void k1_keys(const int* __restrict__ coords, int* __restrict__ keys,
                        u32* __restrict__ lut) {
  int i = blockIdx.x * 256 + threadIdx.x;
  if (i >= NPTS) return;
  int4 c4 = *(const int4*)(coords + i * 4);
  int k = (c4.w << 21) | ((c4.x >> 1) << 14) | ((c4.y >> 1) << 7) | (c4.z >> 1);
  keys[i] = k;
  atomicAdd(&lut[k], 1u);   // count points per voxel (~600k atomics total)
}

// ---- K2a: per-chunk occupied-voxel counts (contention-free reduction) -------
__global__ void k2a_part(const u32* __restrict__ lut, u32* __restrict__ partials) {
  __shared__ u32 sd[256];
  int blk = blockIdx.x, t = threadIdx.x;
  const u32* p = lut + blk * CHUNK;
  u32 s = 0;
  for (int j = t; j < CHUNK; j += 256) s += (p[j] != 0u);
  sd[t] = s; __syncthreads();
  for (int o = 128; o > 0; o >>= 1) { if (t < o) sd[t] += sd[t + o]; __syncthreads(); }
  if (t == 0) partials[blk] = sd[0];
}

// ---- K2b: scan the 1024 partials (exclusive) + total U ----------------------
__global__ void k2b_top(u32* __restrict__ partials) {
  __shared__ u32 sh[NPART];
  int t = threadIdx.x;   // 1024 threads
  u32 x = partials[t];
  sh[t] = x; __syncthreads();
  for (int off = 1; off < NPART; off <<= 1) {
    u32 add = (t >= off) ? sh[t - off] : 0u;
    __syncthreads();
    sh[t] += add;
    __syncthreads();
  }
  partials[t] = sh[t] - x;                       // exclusive
  if (t == NPART - 1) partials[NPART] = sh[t];   // total unique count U
}

// ---- K2c: fill lut ((rank+1)|multi<<31 or 0), r2k, zero multi f32 rows ------
__global__ void k2c_fill(u32* __restrict__ lut, const u32* __restrict__ partials,
                         int* __restrict__ r2k, float* __restrict__ fds32) {
  __shared__ u32 tsum[256];
  int blk = blockIdx.x, t = threadIdx.x;
  int base = blk * CHUNK + t * 16;
  u32 loc[16]; u32 s = 0;
#pragma unroll
  for (int j = 0; j < 16; j++) { loc[j] = lut[base + j]; s += (loc[j] != 0u); }
  tsum[t] = s; __syncthreads();
  for (int off = 1; off < 256; off <<= 1) {
    u32 add = (t >= off) ? tsum[t - off] : 0u;
    __syncthreads();
    tsum[t] += add;
    __syncthreads();
  }
  u32 rank = partials[blk] + tsum[t] - s;   // exclusive rank for first elem
#pragma unroll
  for (int j = 0; j < 16; j++) {
    if (loc[j]) {
      u32 flag = (loc[j] > 1u) ? 0x80000000u : 0u;
      lut[base + j] = (rank + 1u) | flag;
      r2k[rank] = base + j;
      if (flag) {   // zero the f32 accumulation row for multi-point voxels
        float4 z = {0.f, 0.f, 0.f, 0.f};
        float* d = fds32 + ((size_t)rank << 6);
#pragma unroll
        for (int c = 0; c < 16; c++) *(float4*)(d + c * 4) = z;
      }
      rank++;
    } else lut[base + j] = 0u;
  }
}

// ---- K3: fused segment-sum: singles -> bf16 direct, multis -> f32 atomics ---
__global__ void k3_seg(const float* __restrict__ feats, const int* __restrict__ keys,
                       const u32* __restrict__ lut, float* __restrict__ fds32,
                       u16* __restrict__ fdsb) {
  int idx = blockIdx.x * 256 + threadIdx.x;   // NPTS*16 threads, 4 ch each
  if (idx >= NPTS * 16) return;
  int i = idx >> 4, q = (idx & 15) << 2;
  u32 lv = lut[keys[i]];
  u32 r = (lv & 0x7fffffffu) - 1u;
  float4 v = *(const float4*)(feats + (size_t)i * 64 + q);
  if (lv >> 31) {               // ~13% of points: shared voxel, accumulate f32
    float* dst = fds32 + ((size_t)r << 6) + q;
    atomicAdd(dst + 0, v.x); atomicAdd(dst + 1, v.y);
    atomicAdd(dst + 2, v.z); atomicAdd(dst + 3, v.w);
  } else {                      // ~87%: sole occupant, convert + plain store
    ushort4 o;
    o.x = f2bf(v.x); o.y = f2bf(v.y); o.z = f2bf(v.z); o.w = f2bf(v.w);
    *(ushort4*)(fdsb + ((size_t)r << 6) + q) = o;
  }
}

// ---- K3b: convert only multi-voxel rows f32 -> bf16 -------------------------
__global__ void k3b_fix(const int* __restrict__ r2k, const u32* __restrict__ lut,
                        const u32* __restrict__ pU,
                        const float* __restrict__ fds32, u16* __restrict__ fdsb) {
  int idx = blockIdx.x * 256 + threadIdx.x;   // NPTS*4 threads, 16 ch each
  int r = idx >> 2;
  if (r >= (int)(*pU)) return;
  u32 lv = lut[r2k[r]];
  if (!(lv >> 31)) return;
  int q = (idx & 3) << 4;
  const float* src = fds32 + ((size_t)r << 6) + q;
  u16* dst = fdsb + ((size_t)r << 6) + q;
#pragma unroll
  for (int j = 0; j < 4; j++) {
    float4 v = *(const float4*)(src + j * 4);
    ushort4 o;
    o.x = f2bf(v.x); o.y = f2bf(v.y); o.z = f2bf(v.z); o.w = f2bf(v.w);
    *(ushort4*)(dst + j * 4) = o;
  }
}

// ---- K4: symmetric-wave asm-pipelined gather-GEMM + BN/ReLU (R15 best) ------
// Block = 256 thr (4 SYMMETRIC waves), 64 output rows. Every wave both
// produces (its 16 rows: lane l gathers row w*16+(l>>2), bytes (l&3)*32,
// 2x16B branchless asm loads, zero-row sentinel -> static vmcnt) and
// consumes (its 16-cout block over all 64 rows: 8 ds_reads + 8 MFMA).
// Schedule (FIFO-verified): P(T)@T-5, L(T)@T-3, B(T)@T-2, DSW(T)@T-1,
// consume@T. Per BODY(K): wait vmcnt(NW) retires exactly the 2-interval-old
// batch {L(K+1),P(K+3),B(K)}; issues {L(K+3),P(K+5),B(K+2)} stay in flight
// across the raw s_barrier. NW(K)=2[K+1<27]+2[K+2<27]+[K+4<27].
// Rings: rgA[T%3], bB[T%3], lvr[T&3], LDS slot T&1 (bank rotation, 0 confl).
__global__ __launch_bounds__(256) void k4_conv(
    const u32* __restrict__ lut, const int* __restrict__ r2k,
    const u16* __restrict__ fdsb, const u16* __restrict__ Wt,
    const u32* __restrict__ pU, const float* __restrict__ ab,
    float* __restrict__ out) {
  __shared__ __align__(16) char ldsA[2][8192];   // ring-2: 64 rows x 128B
  const u32 U = *pU;
  int tid = threadIdx.x;
  int w = tid >> 6, l = tid & 63;
  // m204 bijective XCD swizzle (grid 9375 not divisible by 8)
  int bid = blockIdx.x;
  int nwg = (int)gridDim.x, q = nwg >> 3, rr = nwg & 7;
  int xcd = bid & 7, t8 = bid >> 3;
  int swz = (xcd < rr ? xcd * (q + 1) : rr * (q + 1) + (xcd - rr) * q) + t8;
  int rbase = swz * 64;

  int lr = (w << 4) + (l >> 2);        // this lane's produced row (0..63)
  int col = l & 15, kg = l >> 4;

  // key decode for produced row (4 lanes/row, coalesced broadcast)
  int key = -1, x = 0, y = 0, z = 0;
  {
    int r = rbase + lr;
    key = ((u32)r < U) ? r2k[r] : -1;
    z = key & 127; y = (key >> 7) & 127; x = (key >> 14) & 127;
  }

  u32 lvr[4];        // probe ring: P(T)@T-5, used by L(T)@T-3
  i32x4 rgA[3][2];   // gather ring: L(T)@T-3 -> DSW(T)@T-1
  i32x4 bB[3][2];    // B ring: B(T)@T-2 -> MFMA@T
  f32x4 acc[4] = {};

#define P_(T) { \
    const int dx_ = (T) / 9 - 1, dy_ = ((T) / 3) % 3 - 1, dz_ = (T) % 3 - 1; \
    int nx_ = x + dx_, ny_ = y + dy_, nz_ = z + dz_; \
    bool ok_ = (key >= 0) & ((u32)nx_ < 128u) & ((u32)ny_ < 128u) & ((u32)nz_ < 128u); \
    const u32* pp_ = lut + (ok_ ? (key + dx_ * 16384 + dy_ * 128 + dz_) : NKEYS); \
    asm volatile("global_load_dword %0, %1, off" \
                 : "=&v"(lvr[(T) & 3]) : "v"(pp_) : "memory"); }

  // branchless 2x16B gather of this lane's quarter-row; miss -> zero row
#define L_(T) { \
    u32 lv_ = lvr[(T) & 3]; \
    u32 row_ = lv_ ? ((lv_ & 0x7fffffffu) - 1u) : (u32)NPTS; \
    const char* fr_ = (const char*)(fdsb + ((size_t)row_ << 6)) + ((l & 3) << 5); \
    asm volatile("global_load_dwordx4 %0, %1, off" \
                 : "=&v"(rgA[(T) % 3][0]) : "v"(fr_) : "memory"); \
    asm volatile("global_load_dwordx4 %0, %1, off offset:16" \
                 : "=&v"(rgA[(T) % 3][1]) : "v"(fr_) : "memory"); }

#define B_(T) { \
    const u16* wb_ = Wt + ((T) << 12) + (((w << 4) + col) << 6) + (kg << 3); \
    asm volatile("global_load_dwordx4 %0, %1, off" \
                 : "=&v"(bB[(T) % 3][0]) : "v"(wb_) : "memory"); \
    asm volatile("global_load_dwordx4 %0, %1, off offset:64" \
                 : "=&v"(bB[(T) % 3][1]) : "v"(wb_) : "memory"); }

  // LDS write of this lane's 2 chunks, bank rotation (rot by row&7)
#define DSW_(T) { \
    char* dst_ = &ldsA[(T) & 1][lr * 128]; \
    int r7_ = lr & 7, c0_ = (l & 3) << 1; \
    *(i32x4*)(dst_ + (((c0_ + r7_) & 7) << 4))     = rgA[(T) % 3][0]; \
    *(i32x4*)(dst_ + (((c0_ + 1 + r7_) & 7) << 4)) = rgA[(T) % 3][1]; }

#define CONSUME(K) { \
    short8 b0_ = *(short8*)&bB[(K) % 3][0]; \
    short8 b1_ = *(short8*)&bB[(K) % 3][1]; \
    const char* slab_ = &ldsA[(K) & 1][0]; \
    _Pragma("unroll") for (int rt = 0; rt < 4; rt++) { \
      int row_ = (rt << 4) + col; \
      const char* rp_ = slab_ + row_ * 128; \
      int r7_ = row_ & 7; \
      short8 a0_ = *(const short8*)(rp_ + (((kg + r7_) & 7) << 4)); \
      short8 a1_ = *(const short8*)(rp_ + (((kg + 4 + r7_) & 7) << 4)); \
      acc[rt] = __builtin_amdgcn_mfma_f32_16x16x32_bf16(a0_, b0_, acc[rt], 0, 0, 0); \
      acc[rt] = __builtin_amdgcn_mfma_f32_16x16x32_bf16(a1_, b1_, acc[rt], 0, 0, 0); } }

#define WAITC(N) { asm volatile("s_waitcnt vmcnt(%0)" :: "n"(N) : "memory"); \
                   __builtin_amdgcn_sched_barrier(0); }
#define BAR() { \
    asm volatile("" ::: "memory"); \
    asm volatile("s_waitcnt lgkmcnt(0)" ::: "memory"); \
    __builtin_amdgcn_s_barrier(); \
    asm volatile("" ::: "memory"); }

  // prologue (FIFO after: [L1,L1,P3,B0,B0,B1,B1,P4,L2,L2] = 10 outstanding)
  P_(0) P_(1) P_(2)
  WAITC(0)
  L_(0) L_(1) P_(3) B_(0) B_(1)
  WAITC(7)
  DSW_(0)
  P_(4) L_(2)
  BAR()

  // NW(K) = size of BODY(K-1)'s issue batch (retire the 2-interval-old batch)
#define NW(K) (2 * ((K) + 1 < 27) + 2 * ((K) + 2 < 27) + 1 * ((K) + 4 < 27))
#define BODY(K) { \
    WAITC(NW(K)) \
    if ((K) + 1 < 27) DSW_((K) + 1) \
    if ((K) + 3 < 27) L_((K) + 3) \
    if ((K) + 5 < 27) P_((K) + 5) \
    if ((K) + 2 < 27) B_((K) + 2) \
    CONSUME(K) \
    BAR() }

  BODY(0)  BODY(1)  BODY(2)  BODY(3)  BODY(4)  BODY(5)  BODY(6)
  BODY(7)  BODY(8)  BODY(9)  BODY(10) BODY(11) BODY(12) BODY(13)
  BODY(14) BODY(15) BODY(16) BODY(17) BODY(18) BODY(19) BODY(20)
  BODY(21) BODY(22) BODY(23) BODY(24) BODY(25) BODY(26)

#undef P_
#undef L_
#undef B_
#undef DSW_
#undef CONSUME
#undef WAITC
#undef BAR
#undef NW
#undef BODY

  // epilogue: BN + ReLU for this wave's 16-cout block, zeros for invalid rows
  {
    int c = (w << 4) | col;
    float al = ab[c], be = ab[64 + c];
#pragma unroll
    for (int rt = 0; rt < 4; rt++) {
#pragma unroll
      for (int i = 0; i < 4; i++) {
        int r = rbase + (rt << 4) + (kg << 2) + i;
        if (r >= NPTS) continue;
        bool valid = ((u32)r < U);
        float vv = 0.f;
        if (valid) {
          vv = fmaf(acc[rt][i], al, be);
          vv = vv > 0.f ? vv : 0.f;
        }
        out[((size_t)r << 6) + c] = vv;
      }
    }
  }
}

extern "C" void kernel_launch(void* const* d_in, const int* in_sizes, int n_in,
                              void* d_out, int out_size, void* d_ws, size_t ws_size,
                              hipStream_t stream) {
  const int*   coords = (const int*)d_in[0];
  const float* feats  = (const float*)d_in[1];
  const float* W      = (const float*)d_in[2];
  const float* bns    = (const float*)d_in[3];
  const float* bnb    = (const float*)d_in[4];
  const float* bnm    = (const float*)d_in[5];
  const float* bnv    = (const float*)d_in[6];
  float* out = (float*)d_out;

  char* ws = (char*)d_ws;
  size_t off = 0;
  auto alloc = [&](size_t bytes) -> void* {
    void* p = ws + off;
    off += (bytes + 255) & ~(size_t)255;
    return p;
  };
  u32* lut      = (u32*)alloc((size_t)(NKEYS + 1) * 4);  // +1 zero sentinel
  u32* partials = (u32*)alloc((NPART + 8) * 4);
  int* keys     = (int*)alloc((size_t)NPTS * 4);
  int* r2k      = (int*)alloc((size_t)NPTS * 4);
  u16* fdsb     = (u16*)alloc((size_t)(NPTS + 1) * 64 * 2);  // +1 zero row
  u16* Wt       = (u16*)alloc((size_t)27 * 4096 * 2);
  float* ab     = (float*)alloc(128 * 4);
  (void)ws_size; (void)out_size; (void)n_in; (void)in_sizes;

  float* fds32 = out;   // d_out doubles as f32 staging for multi-point voxels

  hipMemsetAsync(lut, 0, (size_t)(NKEYS + 1) * 4, stream);
  hipMemsetAsync(fdsb + (size_t)NPTS * 64, 0, 128, stream);   // zero row

  k0a_bn<<<1, 64, 0, stream>>>(bns, bnb, bnm, bnv, ab);
  k0b_wt<<<(27 * 4096 + 255) / 256, 256, 0, stream>>>(W, Wt);
  k1_keys<<<(NPTS + 255) / 256, 256, 0, stream>>>(coords, keys, lut);
  k2a_part<<<NPART, 256, 0, stream>>>(lut, partials);
  k2b_top<<<1, NPART, 0, stream>>>(partials);
  k2c_fill<<<NPART, 256, 0, stream>>>(lut, partials, r2k, fds32);
  k3_seg<<<(NPTS * 16 + 255) / 256, 256, 0, stream>>>(feats, keys, lut, fds32, fdsb);
  k3b_fix<<<(NPTS * 4 + 255) / 256, 256, 0, stream>>>(r2k, lut, partials + NPART, fds32, fdsb);
  // 64 rows per block; 9375 blocks, bijective XCD swizzle in-kernel
  k4_conv<<<(NPTS + 63) / 64, 256, 0, stream>>>(lut, r2k, fdsb, Wt,
                                                partials + NPART, ab, out);
}